// Round 1
// baseline (1079.300 us; speedup 1.0000x reference)
//
#include <hip/hip_runtime.h>
#include <stdint.h>

typedef __attribute__((ext_vector_type(8))) __bf16 bf16x8;
typedef __attribute__((ext_vector_type(4))) float f32x4;

__device__ __forceinline__ unsigned short f2bf(float f) {
  unsigned u = __float_as_uint(f);
  u += 0x7FFFu + ((u >> 16) & 1u);
  return (unsigned short)(u >> 16);
}

__device__ __forceinline__ void gload16(const void* g, void* lds) {
  __builtin_amdgcn_global_load_lds((const __attribute__((address_space(1))) void*)g,
                                   (__attribute__((address_space(3))) void*)lds, 16, 0, 0);
}

// ---------------- elementwise / prep kernels ----------------

// row L2-normalize (f32 in) -> bf16 out. one block per row, cols % 1024 == 0
__global__ __launch_bounds__(256) void rownorm_bf16(const float* __restrict__ x,
                                                    unsigned short* __restrict__ y,
                                                    int cols) {
  const int row = blockIdx.x;
  const float4* x4 = (const float4*)(x + (size_t)row * cols);
  const int n4 = cols >> 2;
  float s = 0.f;
  for (int i = threadIdx.x; i < n4; i += 256) {
    float4 t = x4[i];
    s += t.x * t.x + t.y * t.y + t.z * t.z + t.w * t.w;
  }
#pragma unroll
  for (int o = 32; o >= 1; o >>= 1) s += __shfl_xor(s, o, 64);
  __shared__ float red[4];
  if ((threadIdx.x & 63) == 0) red[threadIdx.x >> 6] = s;
  __syncthreads();
  const float tot = red[0] + red[1] + red[2] + red[3];
  const float sc = 1.0f / sqrtf(tot + 1e-6f);
  ushort4* y4 = (ushort4*)(y + (size_t)row * cols);
  for (int i = threadIdx.x; i < n4; i += 256) {
    float4 t = x4[i];
    ushort4 o;
    o.x = f2bf(t.x * sc); o.y = f2bf(t.y * sc);
    o.z = f2bf(t.z * sc); o.w = f2bf(t.w * sc);
    y4[i] = o;
  }
}

// plain f32 -> bf16 convert, n4 = number of float4s
__global__ __launch_bounds__(256) void convert_bf16(const float* __restrict__ x,
                                                    unsigned short* __restrict__ y,
                                                    long n4) {
  long i = (long)blockIdx.x * 256 + threadIdx.x;
  const long stride = (long)gridDim.x * 256;
  for (; i < n4; i += stride) {
    float4 t = ((const float4*)x)[i];
    ushort4 o;
    o.x = f2bf(t.x); o.y = f2bf(t.y); o.z = f2bf(t.z); o.w = f2bf(t.w);
    ((ushort4*)y)[i] = o;
  }
}

// f32 [rows][cols] contiguous -> bf16 into dst with row stride ld at col offset off
__global__ __launch_bounds__(256) void convert_strided_bf16(const float* __restrict__ x,
                                                            unsigned short* __restrict__ y,
                                                            int rows, int cols, int ld, int off) {
  const int c4n = cols >> 2;
  const int n4 = rows * c4n;
  for (int i = blockIdx.x * 256 + threadIdx.x; i < n4; i += gridDim.x * 256) {
    const int r = i / c4n;
    const int c4 = i - r * c4n;
    float4 t = ((const float4*)x)[i];
    ushort4 o;
    o.x = f2bf(t.x); o.y = f2bf(t.y); o.z = f2bf(t.z); o.w = f2bf(t.w);
    *(ushort4*)(y + (size_t)r * ld + off + c4 * 4) = o;
  }
}

// x [R][C] f32  ->  y [C][R] bf16   (64x64 LDS tiles)
__global__ __launch_bounds__(256) void transpose_bf16(const float* __restrict__ x,
                                                      unsigned short* __restrict__ y,
                                                      int R, int C) {
  __shared__ float tile[64][65];
  const int r0 = blockIdx.y * 64;
  const int c0 = blockIdx.x * 64;
#pragma unroll
  for (int i = 0; i < 16; ++i) {
    int lin = i * 256 + threadIdx.x;
    int r = lin >> 6, c = lin & 63;
    tile[r][c] = x[(size_t)(r0 + r) * C + c0 + c];
  }
  __syncthreads();
#pragma unroll
  for (int i = 0; i < 16; ++i) {
    int lin = i * 256 + threadIdx.x;
    int tr = lin >> 6, tc = lin & 63;
    y[(size_t)(c0 + tr) * R + r0 + tc] = f2bf(tile[tc][tr]);
  }
}

// ---------------- sparsemax ----------------
// one block (256 thr) per row of 8192; z in regs (32/thread);
// tau solves sum(max(z-tau,0))=1 via 32-step bisection on [max-1, max].
__global__ __launch_bounds__(256) void sparsemax_bf16(const float* __restrict__ sim,
                                                      unsigned short* __restrict__ w,
                                                      int Mc) {
  const int row = blockIdx.x;
  const float4* z4 = (const float4*)(sim + (size_t)row * Mc);
  float z[32];
#pragma unroll
  for (int i = 0; i < 8; ++i) {
    float4 v = z4[i * 256 + threadIdx.x];
    z[i * 4 + 0] = v.x; z[i * 4 + 1] = v.y; z[i * 4 + 2] = v.z; z[i * 4 + 3] = v.w;
  }
  float mx = z[0];
#pragma unroll
  for (int j = 1; j < 32; ++j) mx = fmaxf(mx, z[j]);
#pragma unroll
  for (int o = 32; o >= 1; o >>= 1) mx = fmaxf(mx, __shfl_xor(mx, o, 64));
  __shared__ float red[4];
  const int wv = threadIdx.x >> 6, ln = threadIdx.x & 63;
  if (ln == 0) red[wv] = mx;
  __syncthreads();
  mx = fmaxf(fmaxf(red[0], red[1]), fmaxf(red[2], red[3]));

  float lo = mx - 1.0f, hi = mx;
  for (int it = 0; it < 32; ++it) {
    const float tau = 0.5f * (lo + hi);
    float s = 0.f;
#pragma unroll
    for (int j = 0; j < 32; ++j) s += fmaxf(z[j] - tau, 0.f);
#pragma unroll
    for (int o = 32; o >= 1; o >>= 1) s += __shfl_xor(s, o, 64);
    __syncthreads();              // WAR protection on red[]
    if (ln == 0) red[wv] = s;
    __syncthreads();
    s = red[0] + red[1] + red[2] + red[3];
    if (s > 1.0f) lo = tau; else hi = tau;
  }
  const float tau = 0.5f * (lo + hi);
  unsigned short* wrow = w + (size_t)row * Mc;
#pragma unroll
  for (int i = 0; i < 8; ++i) {
    ushort4 o;
    o.x = f2bf(fmaxf(z[i * 4 + 0] - tau, 0.f));
    o.y = f2bf(fmaxf(z[i * 4 + 1] - tau, 0.f));
    o.z = f2bf(fmaxf(z[i * 4 + 2] - tau, 0.f));
    o.w = f2bf(fmaxf(z[i * 4 + 3] - tau, 0.f));
    ((ushort4*)wrow)[i * 256 + threadIdx.x] = o;
  }
}

// ---------------- GEMM (m97 structure) ----------------
// C[M,N] = A[M,K] * Bt[N,K]^T, bf16 in, f32 acc. 128x128 tile, BK=32,
// 4 waves, each 64x64 (4x4 fragments of 16x16x32 MFMA).
// EPI 0: store f32 (ldc stride). EPI 1: +bias, relu, store bf16 (ldc).
// EPI 2: +bias, store f32 to stride ncols, only col<ncols.
template <int EPI>
__global__ __launch_bounds__(256, 2) void gemm_bt(
    const unsigned short* __restrict__ A, const unsigned short* __restrict__ Bt,
    const float* __restrict__ bias, float* __restrict__ Cf,
    unsigned short* __restrict__ Cb, int M, int N, int K, int ldc, int ncols) {
  __shared__ __align__(16) unsigned short Al[128 * 32];
  __shared__ __align__(16) unsigned short Bl[128 * 32];

  const int tid = threadIdx.x;
  const int wave = tid >> 6;
  const int lane = tid & 63;
  const int bm = blockIdx.y * 128;
  const int bn = blockIdx.x * 128;
  const int wr = (wave >> 1) * 64;
  const int wc = (wave & 1) * 64;

  f32x4 acc[4][4] = {};

  const int srow = tid >> 2;            // 0..63
  const int scol = (tid & 3) * 8;       // bf16 col within BK
  const unsigned short* Ag = A + (size_t)(bm + srow) * K + scol;
  const unsigned short* Bg = Bt + (size_t)(bn + srow) * K + scol;
  char* Alb = (char*)Al + wave * 1024;
  char* Blb = (char*)Bl + wave * 1024;

  const int fr = lane & 15;
  const int kq = lane >> 4;
  const unsigned short* Ard = Al + (wr + fr) * 32 + kq * 8;
  const unsigned short* Brd = Bl + (wc + fr) * 32 + kq * 8;

  for (int kt = 0; kt < K; kt += 32) {
    gload16(Ag + kt, Alb);
    gload16(Ag + kt + (size_t)64 * K, Alb + 4096);
    gload16(Bg + kt, Blb);
    gload16(Bg + kt + (size_t)64 * K, Blb + 4096);
    __syncthreads();   // drains vmcnt -> LDS tiles ready
    bf16x8 af[4], bfr[4];
#pragma unroll
    for (int m = 0; m < 4; ++m) af[m] = *(const bf16x8*)(Ard + m * 16 * 32);
#pragma unroll
    for (int n = 0; n < 4; ++n) bfr[n] = *(const bf16x8*)(Brd + n * 16 * 32);
#pragma unroll
    for (int m = 0; m < 4; ++m)
#pragma unroll
      for (int n = 0; n < 4; ++n)
        acc[m][n] = __builtin_amdgcn_mfma_f32_16x16x32_bf16(af[m], bfr[n], acc[m][n], 0, 0, 0);
    __syncthreads();   // all reads done before next stage overwrites
  }

  const int fq = lane >> 4;
#pragma unroll
  for (int m = 0; m < 4; ++m) {
    const int row0 = bm + wr + m * 16 + fq * 4;
#pragma unroll
    for (int n = 0; n < 4; ++n) {
      const int col = bn + wc + n * 16 + fr;
#pragma unroll
      for (int r = 0; r < 4; ++r) {
        float v = acc[m][n][r];
        if constexpr (EPI == 0) {
          Cf[(size_t)(row0 + r) * ldc + col] = v;
        } else if constexpr (EPI == 1) {
          v = fmaxf(v + bias[col], 0.0f);
          Cb[(size_t)(row0 + r) * ldc + col] = f2bf(v);
        } else {
          if (col < ncols) Cf[(size_t)(row0 + r) * ncols + col] = v + bias[col];
        }
      }
    }
  }
}

// ---------------- launch ----------------
extern "C" void kernel_launch(void* const* d_in, const int* in_sizes, int n_in,
                              void* d_out, int out_size, void* d_ws, size_t ws_size,
                              hipStream_t stream) {
  const float* enc  = (const float*)d_in[0];
  const float* mem  = (const float*)d_in[1];
  const float* fw1  = (const float*)d_in[2];
  const float* fb1  = (const float*)d_in[3];
  const float* fw2  = (const float*)d_in[4];
  const float* fb2  = (const float*)d_in[5];
  float* out = (float*)d_out;

  const int B = 4096, M = 8192, D = 2048, HID = 8192, OUT = 1000, OUTP = 1024;

  char* p = (char*)d_ws;
  auto alloc = [&](size_t bytes) {
    char* r = p;
    p += (bytes + 255) & ~(size_t)255;
    return r;
  };
  unsigned short* encN = (unsigned short*)alloc((size_t)B * D * 2);     // 16 MB
  unsigned short* memN = (unsigned short*)alloc((size_t)M * D * 2);     // 32 MB
  unsigned short* memT = (unsigned short*)alloc((size_t)D * M * 2);     // 32 MB
  unsigned short* w1   = (unsigned short*)alloc((size_t)HID * 2 * D * 2); // 64 MB
  unsigned short* w2   = (unsigned short*)alloc((size_t)OUTP * HID * 2);  // 16 MB
  unsigned short* wts  = (unsigned short*)alloc((size_t)B * M * 2);     // 64 MB
  char* arena = alloc((size_t)B * M * 4);                               // 128 MB
  float* sim = (float*)arena;                               // [B][M] f32 (dies after sparsemax)
  float* mv  = (float*)arena;                               // [B][D] f32 (0..32MB)
  unsigned short* fin = (unsigned short*)(arena + (size_t)32 * 1024 * 1024); // [B][2D] bf16
  unsigned short* hid = (unsigned short*)(arena + (size_t)64 * 1024 * 1024); // [B][HID] bf16

  // prep: normalize + casts + mem transpose
  rownorm_bf16<<<B, 256, 0, stream>>>(enc, encN, D);
  rownorm_bf16<<<M, 256, 0, stream>>>(mem, memN, D);
  transpose_bf16<<<dim3(D / 64, M / 64), 256, 0, stream>>>(mem, memT, M, D);
  convert_bf16<<<2048, 256, 0, stream>>>(fw1, w1, (long)HID * 2 * D / 4);
  convert_bf16<<<2048, 256, 0, stream>>>(fw2, w2, (long)OUT * HID / 4);

  // sim = encN @ memN^T   [B, M]
  gemm_bt<0><<<dim3(M / 128, B / 128), 256, 0, stream>>>(encN, memN, nullptr, sim, nullptr,
                                                         B, M, D, M, 0);
  // sparsemax rows -> weights (bf16)
  sparsemax_bf16<<<B, 256, 0, stream>>>(sim, wts, M);
  // mv = wts @ mem   (memT is mem^T as [D][M])
  gemm_bt<0><<<dim3(D / 128, B / 128), 256, 0, stream>>>(wts, memT, nullptr, mv, nullptr,
                                                         B, D, M, D, 0);
  // final_input = [enc, mv] as bf16 [B][2D]
  convert_strided_bf16<<<2048, 256, 0, stream>>>(enc, fin, B, D, 2 * D, 0);
  convert_strided_bf16<<<2048, 256, 0, stream>>>(mv, fin, B, D, 2 * D, D);
  // hidden = relu(final @ fc1_w^T + b1) -> bf16
  gemm_bt<1><<<dim3(HID / 128, B / 128), 256, 0, stream>>>(fin, w1, fb1, nullptr, hid,
                                                           B, HID, 2 * D, HID, 0);
  // out = hidden @ fc2_w^T + b2 (only cols < 1000 stored)
  gemm_bt<2><<<dim3(OUTP / 128, B / 128), 256, 0, stream>>>(hid, w2, fb2, out, nullptr,
                                                            B, OUTP, HID, OUT, OUT);
}

// Round 2
// 979.048 us; speedup vs baseline: 1.1024x; 1.1024x over previous
//
#include <hip/hip_runtime.h>
#include <stdint.h>

typedef __attribute__((ext_vector_type(8))) __bf16 bf16x8;
typedef __attribute__((ext_vector_type(4))) float f32x4;

__device__ __forceinline__ unsigned short f2bf(float f) {
  unsigned u = __float_as_uint(f);
  u += 0x7FFFu + ((u >> 16) & 1u);
  return (unsigned short)(u >> 16);
}

__device__ __forceinline__ void gload16(const void* g, void* lds) {
  __builtin_amdgcn_global_load_lds((const __attribute__((address_space(1))) void*)g,
                                   (__attribute__((address_space(3))) void*)lds, 16, 0, 0);
}

// ---------------- elementwise / prep kernels ----------------

__global__ __launch_bounds__(256) void rownorm_bf16(const float* __restrict__ x,
                                                    unsigned short* __restrict__ y,
                                                    int cols) {
  const int row = blockIdx.x;
  const float4* x4 = (const float4*)(x + (size_t)row * cols);
  const int n4 = cols >> 2;
  float s = 0.f;
  for (int i = threadIdx.x; i < n4; i += 256) {
    float4 t = x4[i];
    s += t.x * t.x + t.y * t.y + t.z * t.z + t.w * t.w;
  }
#pragma unroll
  for (int o = 32; o >= 1; o >>= 1) s += __shfl_xor(s, o, 64);
  __shared__ float red[4];
  if ((threadIdx.x & 63) == 0) red[threadIdx.x >> 6] = s;
  __syncthreads();
  const float tot = red[0] + red[1] + red[2] + red[3];
  const float sc = 1.0f / sqrtf(tot + 1e-6f);
  ushort4* y4 = (ushort4*)(y + (size_t)row * cols);
  for (int i = threadIdx.x; i < n4; i += 256) {
    float4 t = x4[i];
    ushort4 o;
    o.x = f2bf(t.x * sc); o.y = f2bf(t.y * sc);
    o.z = f2bf(t.z * sc); o.w = f2bf(t.w * sc);
    y4[i] = o;
  }
}

__global__ __launch_bounds__(256) void convert_bf16(const float* __restrict__ x,
                                                    unsigned short* __restrict__ y,
                                                    long n4) {
  long i = (long)blockIdx.x * 256 + threadIdx.x;
  const long stride = (long)gridDim.x * 256;
  for (; i < n4; i += stride) {
    float4 t = ((const float4*)x)[i];
    ushort4 o;
    o.x = f2bf(t.x); o.y = f2bf(t.y); o.z = f2bf(t.z); o.w = f2bf(t.w);
    ((ushort4*)y)[i] = o;
  }
}

__global__ __launch_bounds__(256) void convert_strided_bf16(const float* __restrict__ x,
                                                            unsigned short* __restrict__ y,
                                                            int rows, int cols, int ld, int off) {
  const int c4n = cols >> 2;
  const int n4 = rows * c4n;
  for (int i = blockIdx.x * 256 + threadIdx.x; i < n4; i += gridDim.x * 256) {
    const int r = i / c4n;
    const int c4 = i - r * c4n;
    float4 t = ((const float4*)x)[i];
    ushort4 o;
    o.x = f2bf(t.x); o.y = f2bf(t.y); o.z = f2bf(t.z); o.w = f2bf(t.w);
    *(ushort4*)(y + (size_t)r * ld + off + c4 * 4) = o;
  }
}

__global__ __launch_bounds__(256) void transpose_bf16(const float* __restrict__ x,
                                                      unsigned short* __restrict__ y,
                                                      int R, int C) {
  __shared__ float tile[64][65];
  const int r0 = blockIdx.y * 64;
  const int c0 = blockIdx.x * 64;
#pragma unroll
  for (int i = 0; i < 16; ++i) {
    int lin = i * 256 + threadIdx.x;
    int r = lin >> 6, c = lin & 63;
    tile[r][c] = x[(size_t)(r0 + r) * C + c0 + c];
  }
  __syncthreads();
#pragma unroll
  for (int i = 0; i < 16; ++i) {
    int lin = i * 256 + threadIdx.x;
    int tr = lin >> 6, tc = lin & 63;
    y[(size_t)(c0 + tr) * R + r0 + tc] = f2bf(tile[tc][tr]);
  }
}

// ---------------- sparsemax ----------------
__global__ __launch_bounds__(256) void sparsemax_bf16(const float* __restrict__ sim,
                                                      unsigned short* __restrict__ w,
                                                      int Mc) {
  const int row = blockIdx.x;
  const float4* z4 = (const float4*)(sim + (size_t)row * Mc);
  float z[32];
#pragma unroll
  for (int i = 0; i < 8; ++i) {
    float4 v = z4[i * 256 + threadIdx.x];
    z[i * 4 + 0] = v.x; z[i * 4 + 1] = v.y; z[i * 4 + 2] = v.z; z[i * 4 + 3] = v.w;
  }
  float mx = z[0];
#pragma unroll
  for (int j = 1; j < 32; ++j) mx = fmaxf(mx, z[j]);
#pragma unroll
  for (int o = 32; o >= 1; o >>= 1) mx = fmaxf(mx, __shfl_xor(mx, o, 64));
  __shared__ float red[4];
  const int wv = threadIdx.x >> 6, ln = threadIdx.x & 63;
  if (ln == 0) red[wv] = mx;
  __syncthreads();
  mx = fmaxf(fmaxf(red[0], red[1]), fmaxf(red[2], red[3]));

  float lo = mx - 1.0f, hi = mx;
  for (int it = 0; it < 32; ++it) {
    const float tau = 0.5f * (lo + hi);
    float s = 0.f;
#pragma unroll
    for (int j = 0; j < 32; ++j) s += fmaxf(z[j] - tau, 0.f);
#pragma unroll
    for (int o = 32; o >= 1; o >>= 1) s += __shfl_xor(s, o, 64);
    __syncthreads();
    if (ln == 0) red[wv] = s;
    __syncthreads();
    s = red[0] + red[1] + red[2] + red[3];
    if (s > 1.0f) lo = tau; else hi = tau;
  }
  const float tau = 0.5f * (lo + hi);
  unsigned short* wrow = w + (size_t)row * Mc;
#pragma unroll
  for (int i = 0; i < 8; ++i) {
    ushort4 o;
    o.x = f2bf(fmaxf(z[i * 4 + 0] - tau, 0.f));
    o.y = f2bf(fmaxf(z[i * 4 + 1] - tau, 0.f));
    o.z = f2bf(fmaxf(z[i * 4 + 2] - tau, 0.f));
    o.w = f2bf(fmaxf(z[i * 4 + 3] - tau, 0.f));
    ((ushort4*)wrow)[i * 256 + threadIdx.x] = o;
  }
}

// ---------------- GEMM 128x128 (m97 structure) — for narrow-N cases ----------------
template <int EPI>
__global__ __launch_bounds__(256, 2) void gemm_bt(
    const unsigned short* __restrict__ A, const unsigned short* __restrict__ Bt,
    const float* __restrict__ bias, float* __restrict__ Cf,
    unsigned short* __restrict__ Cb, int M, int N, int K, int ldc, int ncols) {
  __shared__ __align__(16) unsigned short Al[128 * 32];
  __shared__ __align__(16) unsigned short Bl[128 * 32];

  const int tid = threadIdx.x;
  const int wave = tid >> 6;
  const int lane = tid & 63;
  const int bm = blockIdx.y * 128;
  const int bn = blockIdx.x * 128;
  const int wr = (wave >> 1) * 64;
  const int wc = (wave & 1) * 64;

  f32x4 acc[4][4] = {};

  const int srow = tid >> 2;
  const int scol = (tid & 3) * 8;
  const unsigned short* Ag = A + (size_t)(bm + srow) * K + scol;
  const unsigned short* Bg = Bt + (size_t)(bn + srow) * K + scol;
  char* Alb = (char*)Al + wave * 1024;
  char* Blb = (char*)Bl + wave * 1024;

  const int fr = lane & 15;
  const int kq = lane >> 4;
  const unsigned short* Ard = Al + (wr + fr) * 32 + kq * 8;
  const unsigned short* Brd = Bl + (wc + fr) * 32 + kq * 8;

  for (int kt = 0; kt < K; kt += 32) {
    gload16(Ag + kt, Alb);
    gload16(Ag + kt + (size_t)64 * K, Alb + 4096);
    gload16(Bg + kt, Blb);
    gload16(Bg + kt + (size_t)64 * K, Blb + 4096);
    __syncthreads();
    bf16x8 af[4], bfr[4];
#pragma unroll
    for (int m = 0; m < 4; ++m) af[m] = *(const bf16x8*)(Ard + m * 16 * 32);
#pragma unroll
    for (int n = 0; n < 4; ++n) bfr[n] = *(const bf16x8*)(Brd + n * 16 * 32);
#pragma unroll
    for (int m = 0; m < 4; ++m)
#pragma unroll
      for (int n = 0; n < 4; ++n)
        acc[m][n] = __builtin_amdgcn_mfma_f32_16x16x32_bf16(af[m], bfr[n], acc[m][n], 0, 0, 0);
    __syncthreads();
  }

  const int fq = lane >> 4;
#pragma unroll
  for (int m = 0; m < 4; ++m) {
    const int row0 = bm + wr + m * 16 + fq * 4;
#pragma unroll
    for (int n = 0; n < 4; ++n) {
      const int col = bn + wc + n * 16 + fr;
#pragma unroll
      for (int r = 0; r < 4; ++r) {
        float v = acc[m][n][r];
        if constexpr (EPI == 0) {
          Cf[(size_t)(row0 + r) * ldc + col] = v;
        } else if constexpr (EPI == 1) {
          v = fmaxf(v + bias[col], 0.0f);
          Cb[(size_t)(row0 + r) * ldc + col] = f2bf(v);
        } else {
          if (col < ncols) Cf[(size_t)(row0 + r) * ncols + col] = v + bias[col];
        }
      }
    }
  }
}

// ---------------- GEMM 256x256, BK=64, 8-wave, 8-phase (HK-style) ----------------
// C[M,N] = A[M,K] * Bt[N,K]^T. bf16 in, f32 acc.
// LDS: 2 buffers x (A 256x64 + B 256x64) bf16 = 128 KiB, st-swizzled
// (byte_in_row ^= (row&7)<<4; staged via pre-swizzled global source).
// Phases per K-tile: quad (mh,nh) = (0,0),(0,1),(1,1),(1,0); 16 MFMA each.
// Staging slots: ph0,ph1 -> next K-tile's B1,A1 (other buffer);
//                ph2,ph3 -> K-tile+2's B0,A0 (current buffer, after reads done).
// vmcnt(4) once per K-tile at ph3 guarantees next K-tile fully landed.
template <int EPI>
__global__ __launch_bounds__(512, 1) void gemm256(
    const unsigned short* __restrict__ A, const unsigned short* __restrict__ Bt,
    const float* __restrict__ bias, float* __restrict__ Cf,
    unsigned short* __restrict__ Cb, int M, int N, int K, int ldc) {
  __shared__ __align__(16) unsigned short lds[2][2][256 * 64];  // [buf][A/B] 128 KiB

  const int tid = threadIdx.x;
  const int wid = tid >> 6;
  const int lane = tid & 63;
  const int wr = wid >> 2;      // 0..1  (M half)
  const int wc = wid & 3;       // 0..3  (N quarter)
  const int fr = lane & 15;
  const int kq = lane >> 4;

  // bijective XCD swizzle (m204)
  const int nx = gridDim.x;
  const int nwg = nx * gridDim.y;
  const int bid = blockIdx.y * nx + blockIdx.x;
  const int q = nwg >> 3, r8 = nwg & 7;
  const int xcd = bid & 7, idx = bid >> 3;
  const int wg = (xcd < r8 ? xcd * (q + 1) : r8 * (q + 1) + (xcd - r8) * q) + idx;
  const int bn = (wg % nx) * 256;
  const int bm = (wg / nx) * 256;

  const int NT = K >> 6;

  // ---- staging: one half-tile (128 rows x 64 cols) = 2 issues of 512x16B
  const int st_r = tid >> 3;                                   // 0..63 row within issue
  const int st_x = (tid & 7) << 4;                             // swizzled byte-in-row
  auto stage_half = [&](int buf, int mat, int half, int kt) {
    const unsigned short* src = mat ? Bt : A;
    const int gb = mat ? bn : bm;
#pragma unroll
    for (int iss = 0; iss < 2; ++iss) {
      const int row = half * 128 + iss * 64 + st_r;
      const int colb = st_x ^ ((row & 7) << 4);                // logical byte-in-row
      const unsigned short* g = src + (size_t)(gb + row) * K + kt * 64 + (colb >> 1);
      char* l = (char*)&lds[buf][mat][0] + (half * 2 + iss) * 8192 + (wid << 10);
      gload16(g, l);
    }
  };

  // ---- fragment reads (per-lane swizzle XOR is lane-constant: (fr&7)<<4)
  const int swz = (fr & 7) << 4;
  auto rdA = [&](int buf, int mh, int m, int kk) -> bf16x8 {
    const int row = wr * 128 + mh * 64 + m * 16 + fr;
    const int off = row * 128 + ((kk * 64 + kq * 16) ^ swz);
    return *(const bf16x8*)((const char*)&lds[buf][0][0] + off);
  };
  auto rdB = [&](int buf, int nh, int n, int kk) -> bf16x8 {
    const int row = wc * 64 + nh * 32 + n * 16 + fr;
    const int off = row * 128 + ((kk * 64 + kq * 16) ^ swz);
    return *(const bf16x8*)((const char*)&lds[buf][1][0] + off);
  };

  f32x4 acc[8][4] = {};
  bf16x8 a[4][2];        // current A half: 4 mfrags x 2 k-slices
  bf16x8 b[2][2][2];     // full B tile:   [nh][nfrag][k-slice]

  // ---- prologue: K-tile 0 (all 4 halves) + K-tile 1 (B0, A0)
  stage_half(0, 1, 0, 0);
  stage_half(0, 0, 0, 0);
  stage_half(0, 1, 1, 0);
  stage_half(0, 0, 1, 0);
  if (NT > 1) {
    stage_half(1, 1, 0, 1);
    stage_half(1, 0, 0, 1);
    asm volatile("s_waitcnt vmcnt(4)" ::: "memory");
  } else {
    asm volatile("s_waitcnt vmcnt(0)" ::: "memory");
  }
  __builtin_amdgcn_sched_barrier(0);
  __builtin_amdgcn_s_barrier();

  for (int kt = 0; kt < NT; ++kt) {
    const int buf = kt & 1, nbuf = buf ^ 1;

    // ===== phase 0: quad (0,0) — reads A(mh0) + B(nh0); stage B1 of kt+1
#pragma unroll
    for (int m = 0; m < 4; ++m) {
      a[m][0] = rdA(buf, 0, m, 0);
      a[m][1] = rdA(buf, 0, m, 1);
    }
#pragma unroll
    for (int n = 0; n < 2; ++n) {
      b[0][n][0] = rdB(buf, 0, n, 0);
      b[0][n][1] = rdB(buf, 0, n, 1);
    }
    if (kt + 1 < NT) stage_half(nbuf, 1, 1, kt + 1);
    __builtin_amdgcn_s_barrier();
    asm volatile("s_waitcnt lgkmcnt(0)" ::: "memory");
    __builtin_amdgcn_sched_barrier(0);
    __builtin_amdgcn_s_setprio(1);
#pragma unroll
    for (int m = 0; m < 4; ++m)
#pragma unroll
      for (int n = 0; n < 2; ++n)
#pragma unroll
        for (int kk = 0; kk < 2; ++kk)
          acc[m][n] = __builtin_amdgcn_mfma_f32_16x16x32_bf16(a[m][kk], b[0][n][kk], acc[m][n], 0, 0, 0);
    __builtin_amdgcn_s_setprio(0);
    __builtin_amdgcn_sched_barrier(0);
    __builtin_amdgcn_s_barrier();

    // ===== phase 1: quad (0,1) — reads B(nh1); stage A1 of kt+1
#pragma unroll
    for (int n = 0; n < 2; ++n) {
      b[1][n][0] = rdB(buf, 1, n, 0);
      b[1][n][1] = rdB(buf, 1, n, 1);
    }
    if (kt + 1 < NT) stage_half(nbuf, 0, 1, kt + 1);
    __builtin_amdgcn_s_barrier();
    asm volatile("s_waitcnt lgkmcnt(0)" ::: "memory");
    __builtin_amdgcn_sched_barrier(0);
    __builtin_amdgcn_s_setprio(1);
#pragma unroll
    for (int m = 0; m < 4; ++m)
#pragma unroll
      for (int n = 0; n < 2; ++n)
#pragma unroll
        for (int kk = 0; kk < 2; ++kk)
          acc[m][n + 2] = __builtin_amdgcn_mfma_f32_16x16x32_bf16(a[m][kk], b[1][n][kk], acc[m][n + 2], 0, 0, 0);
    __builtin_amdgcn_s_setprio(0);
    __builtin_amdgcn_sched_barrier(0);
    __builtin_amdgcn_s_barrier();

    // ===== phase 2: quad (1,1) — reads A(mh1); stage B0 of kt+2 (current buf)
#pragma unroll
    for (int m = 0; m < 4; ++m) {
      a[m][0] = rdA(buf, 1, m, 0);
      a[m][1] = rdA(buf, 1, m, 1);
    }
    if (kt + 2 < NT) stage_half(buf, 1, 0, kt + 2);
    __builtin_amdgcn_s_barrier();
    asm volatile("s_waitcnt lgkmcnt(0)" ::: "memory");
    __builtin_amdgcn_sched_barrier(0);
    __builtin_amdgcn_s_setprio(1);
#pragma unroll
    for (int m = 0; m < 4; ++m)
#pragma unroll
      for (int n = 0; n < 2; ++n)
#pragma unroll
        for (int kk = 0; kk < 2; ++kk)
          acc[m + 4][n + 2] = __builtin_amdgcn_mfma_f32_16x16x32_bf16(a[m][kk], b[1][n][kk], acc[m + 4][n + 2], 0, 0, 0);
    __builtin_amdgcn_s_setprio(0);
    __builtin_amdgcn_sched_barrier(0);
    __builtin_amdgcn_s_barrier();

    // ===== phase 3: quad (1,0) — no reads; stage A0 of kt+2; counted vmcnt
    if (kt + 2 < NT) {
      stage_half(buf, 0, 0, kt + 2);
      asm volatile("s_waitcnt vmcnt(4)" ::: "memory");
    } else {
      asm volatile("s_waitcnt vmcnt(0)" ::: "memory");
    }
    __builtin_amdgcn_sched_barrier(0);
    __builtin_amdgcn_s_barrier();
    __builtin_amdgcn_s_setprio(1);
#pragma unroll
    for (int m = 0; m < 4; ++m)
#pragma unroll
      for (int n = 0; n < 2; ++n)
#pragma unroll
        for (int kk = 0; kk < 2; ++kk)
          acc[m + 4][n] = __builtin_amdgcn_mfma_f32_16x16x32_bf16(a[m][kk], b[0][n][kk], acc[m + 4][n], 0, 0, 0);
    __builtin_amdgcn_s_setprio(0);
    __builtin_amdgcn_sched_barrier(0);
    __builtin_amdgcn_s_barrier();
  }

  // ---- epilogue
  const int fq = lane >> 4;
#pragma unroll
  for (int m = 0; m < 8; ++m) {
    const int row0 = bm + wr * 128 + m * 16 + fq * 4;
#pragma unroll
    for (int n = 0; n < 4; ++n) {
      const int col = bn + wc * 64 + n * 16 + fr;
#pragma unroll
      for (int r = 0; r < 4; ++r) {
        float v = acc[m][n][r];
        if constexpr (EPI == 0) {
          Cf[(size_t)(row0 + r) * ldc + col] = v;
        } else {
          v = fmaxf(v + bias[col], 0.0f);
          Cb[(size_t)(row0 + r) * ldc + col] = f2bf(v);
        }
      }
    }
  }
}

// ---------------- launch ----------------
extern "C" void kernel_launch(void* const* d_in, const int* in_sizes, int n_in,
                              void* d_out, int out_size, void* d_ws, size_t ws_size,
                              hipStream_t stream) {
  const float* enc  = (const float*)d_in[0];
  const float* mem  = (const float*)d_in[1];
  const float* fw1  = (const float*)d_in[2];
  const float* fb1  = (const float*)d_in[3];
  const float* fw2  = (const float*)d_in[4];
  const float* fb2  = (const float*)d_in[5];
  float* out = (float*)d_out;

  const int B = 4096, M = 8192, D = 2048, HID = 8192, OUT = 1000, OUTP = 1024;

  char* p = (char*)d_ws;
  auto alloc = [&](size_t bytes) {
    char* r = p;
    p += (bytes + 255) & ~(size_t)255;
    return r;
  };
  unsigned short* encN = (unsigned short*)alloc((size_t)B * D * 2);
  unsigned short* memN = (unsigned short*)alloc((size_t)M * D * 2);
  unsigned short* memT = (unsigned short*)alloc((size_t)D * M * 2);
  unsigned short* w1   = (unsigned short*)alloc((size_t)HID * 2 * D * 2);
  unsigned short* w2   = (unsigned short*)alloc((size_t)OUTP * HID * 2);
  unsigned short* wts  = (unsigned short*)alloc((size_t)B * M * 2);
  char* arena = alloc((size_t)B * M * 4);
  float* sim = (float*)arena;
  float* mv  = (float*)arena;
  unsigned short* fin = (unsigned short*)(arena + (size_t)32 * 1024 * 1024);
  unsigned short* hid = (unsigned short*)(arena + (size_t)64 * 1024 * 1024);

  rownorm_bf16<<<B, 256, 0, stream>>>(enc, encN, D);
  rownorm_bf16<<<M, 256, 0, stream>>>(mem, memN, D);
  transpose_bf16<<<dim3(D / 64, M / 64), 256, 0, stream>>>(mem, memT, M, D);
  convert_bf16<<<2048, 256, 0, stream>>>(fw1, w1, (long)HID * 2 * D / 4);
  convert_bf16<<<2048, 256, 0, stream>>>(fw2, w2, (long)OUT * HID / 4);

  // sim = encN @ memN^T   [B, M]   (256^2 8-phase)
  gemm256<0><<<dim3(M / 256, B / 256), 512, 0, stream>>>(encN, memN, nullptr, sim, nullptr,
                                                         B, M, D, M);
  sparsemax_bf16<<<B, 256, 0, stream>>>(sim, wts, M);
  // mv = wts @ mem  (N=2048 -> keep 128^2)
  gemm_bt<0><<<dim3(D / 128, B / 128), 256, 0, stream>>>(wts, memT, nullptr, mv, nullptr,
                                                         B, D, M, D, 0);
  convert_strided_bf16<<<2048, 256, 0, stream>>>(enc, fin, B, D, 2 * D, 0);
  convert_strided_bf16<<<2048, 256, 0, stream>>>(mv, fin, B, D, 2 * D, D);
  // hidden = relu(final @ fc1_w^T + b1) -> bf16   (256^2 8-phase)
  gemm256<1><<<dim3(HID / 256, B / 256), 512, 0, stream>>>(fin, w1, fb1, nullptr, hid,
                                                           B, HID, 2 * D, HID);
  // out = hidden @ fc2_w^T + b2 (N=1024 -> keep 128^2)
  gemm_bt<2><<<dim3(OUTP / 128, B / 128), 256, 0, stream>>>(hid, w2, fb2, out, nullptr,
                                                            B, OUTP, HID, OUT, OUT);
}